// Round 9
// baseline (36.036 us; speedup 1.0000x reference)
//
#include <hip/hip_runtime.h>
#include <hip/hip_bf16.h>

#define NB 8
#define NS 4096
#define NH 1152
#define LEN 256

typedef float vf4 __attribute__((ext_vector_type(4)));

// ws layout (int32): counts[2048] | starts[2048] | order[32768]
#define WS_COUNTS 0
#define WS_STARTS 2048
#define WS_ORDER  4096

// Prep: one block per batch. Scan 32KB coords once (vs 2048x redundantly in
// the fused version), histogram + scan + scatter row lists to ws.
__global__ __launch_bounds__(256) void gvp_prep(
        const int* __restrict__ patch, int* __restrict__ ws,
        float* __restrict__ maskout) {
    int b = blockIdx.x;
    int t = threadIdx.x;
    __shared__ int s_seg[NS];
    __shared__ int s_cnt[LEN];
    __shared__ int s_cur[LEN];
    __shared__ int sd[LEN];
    __shared__ int s_max[4];
    __shared__ int s_mult;

    const int2* p2 = (const int2*)(patch + (size_t)b * NS * 2);
    int xs[16], ys[16];
    int m = 0;
    #pragma unroll
    for (int i = 0; i < 16; ++i) {
        int2 v = p2[t + 256 * i];
        int x = v.x < 0 ? 0 : v.x;
        int y = v.y < 0 ? 0 : v.y;
        xs[i] = x; ys[i] = y;
        m = max(m, x);
    }
    #pragma unroll
    for (int off = 32; off > 0; off >>= 1)
        m = max(m, __shfl_down(m, off, 64));
    if ((t & 63) == 0) s_max[t >> 6] = m;
    s_cnt[t] = 0;
    __syncthreads();
    if (t == 0)
        s_mult = (max(max(s_max[0], s_max[1]), max(s_max[2], s_max[3])) + 1) >> 2;
    __syncthreads();
    int mult = s_mult;

    #pragma unroll
    for (int i = 0; i < 16; ++i) {
        int seg = (xs[i] >> 2) + mult * (ys[i] >> 2);   // ref guarantees < LEN
        s_seg[t + 256 * i] = seg;
        atomicAdd(&s_cnt[seg], 1);
    }
    __syncthreads();

    int c = s_cnt[t];
    sd[t] = c;
    __syncthreads();
    for (int off = 1; off < 256; off <<= 1) {
        int v = (t >= off) ? sd[t - off] : 0;
        __syncthreads();
        sd[t] += v;
        __syncthreads();
    }
    int base = sd[t] - c;
    s_cur[t] = base;
    ws[WS_STARTS + b * LEN + t] = b * NS + base;
    ws[WS_COUNTS + b * LEN + t] = c;
    maskout[b * LEN + t] = (c > 0) ? 1.0f : 0.0f;
    __syncthreads();

    #pragma unroll
    for (int i = 0; i < 16; ++i) {
        int s = t + 256 * i;
        int pos = atomicAdd(&s_cur[s_seg[s]], 1);
        ws[WS_ORDER + b * NS + pos] = s;
    }
}

// Gather: one block per (b,seg). Row list padded to a multiple of 8 with
// rows[0] duplicates -> every iteration runs at full 8-load depth (no
// single-load remainder pockets); the pad contribution is subtracted with
// one L2-hot re-read + fma.
__global__ __launch_bounds__(256) void gvp_gather(
        const float* __restrict__ hidden,
        const int* __restrict__ ws,
        float* __restrict__ out) {
    __shared__ __align__(16) int rows[NS + 8];
    int g = blockIdx.x;                        // b*256 + seg
    int b = g >> 8;
    int t = threadIdx.x;
    int start = ws[WS_STARTS + g];
    int cnt   = ws[WS_COUNTS + g];
    for (int i = t; i < cnt; i += 256) rows[i] = ws[WS_ORDER + start + i];
    __syncthreads();

    vf4* og = (vf4*)(out + (size_t)g * NH);
    if (cnt == 0) {                            // empty segment: zeros
        og[t] = 0.f;
        if (t < 32) og[256 + t] = 0.f;
        return;
    }
    int cnt8 = (cnt + 7) & ~7;
    int pad = cnt8 - cnt;
    if (t < pad) rows[cnt + t] = rows[0];
    __syncthreads();

    // main columns (0..255): full-depth 8-row iterations only
    const float* hb = hidden + (size_t)b * NS * NH;
    vf4 a0 = 0.f, a1 = 0.f;
    for (int r = 0; r < cnt8; r += 8) {
        const vf4* p0 = (const vf4*)(hb + (size_t)rows[r + 0] * NH);
        const vf4* p1 = (const vf4*)(hb + (size_t)rows[r + 1] * NH);
        const vf4* p2r = (const vf4*)(hb + (size_t)rows[r + 2] * NH);
        const vf4* p3 = (const vf4*)(hb + (size_t)rows[r + 3] * NH);
        const vf4* p4 = (const vf4*)(hb + (size_t)rows[r + 4] * NH);
        const vf4* p5 = (const vf4*)(hb + (size_t)rows[r + 5] * NH);
        const vf4* p6 = (const vf4*)(hb + (size_t)rows[r + 6] * NH);
        const vf4* p7 = (const vf4*)(hb + (size_t)rows[r + 7] * NH);
        vf4 v0 = p0[t], v1 = p1[t], v2 = p2r[t], v3 = p3[t];
        vf4 v4 = p4[t], v5 = p5[t], v6 = p6[t], v7 = p7[t];
        v0 += v1; v2 += v3; v4 += v5; v6 += v7;
        v0 += v2; v4 += v6;
        a0 += v0; a1 += v4;
    }
    a0 += a1;
    if (pad) {                                 // subtract pad copies of row0
        vf4 v = ((const vf4*)(hb + (size_t)rows[0] * NH))[t];  // L2-hot
        float fp = (float)pad;
        a0.x -= fp * v.x; a0.y -= fp * v.y; a0.z -= fp * v.z; a0.w -= fp * v.w;
    }

    // tail columns (256..287): balanced round-robin over true cnt
    int l = t & 31;
    int grp = t >> 5;
    vf4 a2 = 0.f;
    for (int r2 = grp; r2 < cnt; r2 += 8)
        a2 += ((const vf4*)(hb + (size_t)rows[r2] * NH))[256 + l];
    __syncthreads();                           // rows[] reads done
    vf4* red = (vf4*)rows;                     // reuse LDS as reduce buffer
    red[t] = a2;
    __syncthreads();

    const float scale = 2.1213203435596424f;   // sqrt(1152) / 16
    og[t] = a0 * scale;
    if (t < 32) {
        vf4 s = 0.f;
        #pragma unroll
        for (int j = 0; j < 8; ++j) s += red[j * 32 + t];
        og[256 + t] = s * scale;
    }
}

extern "C" void kernel_launch(void* const* d_in, const int* in_sizes, int n_in,
                              void* d_out, int out_size, void* d_ws, size_t ws_size,
                              hipStream_t stream) {
    const float* hidden = (const float*)d_in[0];
    const int*   patch  = (const int*)d_in[1];
    // d_in[2] (padding_positions) unused: S != LENGTH branch.
    float* out = (float*)d_out;
    float* maskout = out + (size_t)NB * LEN * NH;   // tuple: pooled then mask
    int* ws = (int*)d_ws;

    gvp_prep  <<<NB,       256, 0, stream>>>(patch, ws, maskout);
    gvp_gather<<<NB * LEN, 256, 0, stream>>>(hidden, ws, out);
}

// Round 10
// 31.872 us; speedup vs baseline: 1.1306x; 1.1306x over previous
//
#include <hip/hip_runtime.h>
#include <hip/hip_bf16.h>

#define NB 8
#define NS 4096
#define NH 1152
#define LEN 256
#define NT 1024                    // 16 waves; 4 sub-groups of 256 threads
#define SEGS 4                     // segments handled per block

typedef float vf4 __attribute__((ext_vector_type(4)));

// Fused pooler, 4 segments per block. Block gq: batch b = gq>>6, segments
// [4*(gq&63), 4*(gq&63)+4). Phase 1 (the per-block preamble that was ~2.2us
// of L2-bound redundancy at 1 seg/block) runs once per FOUR outputs: 512
// blocks x 32KB = 16MB L2 traffic (was 64MB), 4 int2 loads/thread (was 16).
// Phase 2 per 256-thread sub-group is exactly the proven R4 gather:
// float4 col t, 8-row unroll, balanced tail round-robin.
__global__ __launch_bounds__(NT) void gvp_fused(
        const float* __restrict__ hidden,
        const int* __restrict__ patch,
        float* __restrict__ out,
        float* __restrict__ maskout) {
    int gq = blockIdx.x;                       // [0, 512)
    int b = gq >> 6;
    int seg0 = (gq & 63) * SEGS;
    int t = threadIdx.x;
    int sub = t >> 8;                          // sub-group = 4 consecutive waves
    int tl = t & 255;

    __shared__ __align__(16) int rows[NS];     // partitioned by segment
    __shared__ vf4 s_red[NT];                  // 16 KB tail-reduce buffer
    __shared__ int s_max[16];
    __shared__ int s_cnt[SEGS], s_off[SEGS], s_cur[SEGS];
    __shared__ int s_mult;
    if (t < SEGS) s_cnt[t] = 0;

    // ---- Phase 1: scan batch coords once per block (L2-hot) ----
    const int2* p2 = (const int2*)(patch + (size_t)b * NS * 2);
    int pk[4];
    int m = 0;
    #pragma unroll
    for (int i = 0; i < 4; ++i) {
        int2 v = p2[t + NT * i];
        int x = v.x < 0 ? 0 : v.x;
        int y = v.y < 0 ? 0 : v.y;
        pk[i] = x | (y << 16);
        m = max(m, x);
    }
    #pragma unroll
    for (int off = 32; off > 0; off >>= 1)
        m = max(m, __shfl_down(m, off, 64));
    if ((t & 63) == 0) s_max[t >> 6] = m;
    __syncthreads();
    if (t == 0) {
        int mm = s_max[0];
        #pragma unroll
        for (int j = 1; j < 16; ++j) mm = max(mm, s_max[j]);
        s_mult = (mm + 1) >> 2;                // (max_x + 1) // k
    }
    __syncthreads();
    int mult = s_mult;

    // count matches per local segment (~64 of 4096 checks hit the atomic)
    #pragma unroll
    for (int i = 0; i < 4; ++i) {
        int x = pk[i] & 0xffff, y = pk[i] >> 16;
        int d = (x >> 2) + mult * (y >> 2) - seg0;   // ref: seg < LEN
        if ((unsigned)d < SEGS) atomicAdd(&s_cnt[d], 1);
    }
    __syncthreads();
    if (t == 0) {
        int o = 0;
        #pragma unroll
        for (int d = 0; d < SEGS; ++d) { s_off[d] = o; s_cur[d] = o; o += s_cnt[d]; }
    }
    __syncthreads();
    #pragma unroll
    for (int i = 0; i < 4; ++i) {
        int x = pk[i] & 0xffff, y = pk[i] >> 16;
        int d = (x >> 2) + mult * (y >> 2) - seg0;
        if ((unsigned)d < SEGS)
            rows[atomicAdd(&s_cur[d], 1)] = t + NT * i;
    }
    __syncthreads();

    int cnt = s_cnt[sub];
    const int* myrows = rows + s_off[sub];

    // ---- Phase 2 (per sub-group, R4-proven): main cols 0..255 ----
    const float* hb = hidden + (size_t)b * NS * NH;
    vf4 a0 = 0.f, a1 = 0.f;
    int r = 0;
    for (; r + 7 < cnt; r += 8) {
        const vf4* p0 = (const vf4*)(hb + (size_t)myrows[r + 0] * NH);
        const vf4* p1 = (const vf4*)(hb + (size_t)myrows[r + 1] * NH);
        const vf4* p2r = (const vf4*)(hb + (size_t)myrows[r + 2] * NH);
        const vf4* p3 = (const vf4*)(hb + (size_t)myrows[r + 3] * NH);
        const vf4* p4 = (const vf4*)(hb + (size_t)myrows[r + 4] * NH);
        const vf4* p5 = (const vf4*)(hb + (size_t)myrows[r + 5] * NH);
        const vf4* p6 = (const vf4*)(hb + (size_t)myrows[r + 6] * NH);
        const vf4* p7 = (const vf4*)(hb + (size_t)myrows[r + 7] * NH);
        vf4 v0 = p0[tl], v1 = p1[tl], v2 = p2r[tl], v3 = p3[tl];
        vf4 v4 = p4[tl], v5 = p5[tl], v6 = p6[tl], v7 = p7[tl];
        v0 += v1; v2 += v3; v4 += v5; v6 += v7;
        v0 += v2; v4 += v6;
        a0 += v0; a1 += v4;
    }
    for (; r < cnt; ++r)
        a0 += ((const vf4*)(hb + (size_t)myrows[r] * NH))[tl];
    a0 += a1;

    // tail cols 256..287: balanced round-robin over 8 half-wave groups
    int l = tl & 31;
    int grp = tl >> 5;
    vf4 a2 = 0.f;
    for (int r2 = grp; r2 < cnt; r2 += 8)
        a2 += ((const vf4*)(hb + (size_t)myrows[r2] * NH))[256 + l];
    s_red[t] = a2;
    __syncthreads();

    const float scale = 2.1213203435596424f;   // sqrt(1152) / 16
    int g = (b << 8) + seg0 + sub;
    vf4* og = (vf4*)(out + (size_t)g * NH);
    og[tl] = a0 * scale;
    if (tl < 32) {
        vf4 s = 0.f;
        #pragma unroll
        for (int j = 0; j < 8; ++j) s += s_red[(sub << 8) + j * 32 + tl];
        og[256 + tl] = s * scale;
    }
    if (tl == 0) maskout[g] = (cnt > 0) ? 1.0f : 0.0f;
}

extern "C" void kernel_launch(void* const* d_in, const int* in_sizes, int n_in,
                              void* d_out, int out_size, void* d_ws, size_t ws_size,
                              hipStream_t stream) {
    const float* hidden = (const float*)d_in[0];
    const int*   patch  = (const int*)d_in[1];
    // d_in[2] (padding_positions) unused: S != LENGTH branch.
    float* out = (float*)d_out;
    float* maskout = out + (size_t)NB * LEN * NH;   // tuple: pooled then mask

    gvp_fused<<<NB * LEN / SEGS, NT, 0, stream>>>(hidden, patch, out, maskout);
}